// Round 1
// baseline (5643.836 us; speedup 1.0000x reference)
//
#include <hip/hip_runtime.h>
#include <hip/hip_fp16.h>
#include <hip/hip_cooperative_groups.h>

namespace cg = cooperative_groups;

// Sinkhorn-Knopp, factorized M = diag(r) * exp(H) * diag(c).
// V2: ONE persistent cooperative kernel. c in LDS (persistent), r in
// registers (rows are block-private across all 20 iterations), partials
// ping-pong through global with one grid.sync() per iteration.
// E stored fp16 (128 MB -> Infinity-Cache resident across the 20 sweeps).

constexpr int NB    = 64;
constexpr int N     = 1024;
constexpr int SLABS = 8;            // blocks per batch
constexpr int TPB   = 512;          // threads per block (8 waves)
constexpr int WAVES = TPB / 64;     // 8
constexpr int RPB   = N / SLABS;    // 128 rows per block
constexpr int RPW   = RPB / WAVES;  // 16 rows per wave
constexpr int NITER = 20;
constexpr float EPS = 1e-8f;

template <typename ET> struct VT;
template <> struct VT<__half> { static constexpr int CPL = 8, STEPS = 2; };
template <> struct VT<float>  { static constexpr int CPL = 4, STEPS = 4; };

// 16 B load -> CPL floats
__device__ inline void load16B(const __half* p, float* f) {
  uint4 u = *reinterpret_cast<const uint4*>(p);
  float2 t;
  t = __half22float2(*reinterpret_cast<__half2*>(&u.x)); f[0] = t.x; f[1] = t.y;
  t = __half22float2(*reinterpret_cast<__half2*>(&u.y)); f[2] = t.x; f[3] = t.y;
  t = __half22float2(*reinterpret_cast<__half2*>(&u.z)); f[4] = t.x; f[5] = t.y;
  t = __half22float2(*reinterpret_cast<__half2*>(&u.w)); f[6] = t.x; f[7] = t.y;
}
__device__ inline void load16B(const float* p, float* f) {
  float4 v = *reinterpret_cast<const float4*>(p);
  f[0] = v.x; f[1] = v.y; f[2] = v.z; f[3] = v.w;
}

// ---------------------------------------------------------------------------
// One Sinkhorn iteration, inlined into the persistent kernel.
// LAST=false: update c (LDS) + r (regs), emit next column partials.
// LAST=true : update c + r and write M = r*E*c directly.
// ---------------------------------------------------------------------------
template <bool LAST>
__device__ __forceinline__ void sk_iter(
    const __half* __restrict__ E, const float* __restrict__ AIn,
    float* __restrict__ AOut, float* __restrict__ M, float (&r_reg)[RPW],
    float (*red)[N], float* cvec, int b, int s, int tid, int w, int l,
    int i0) {
  // phase a: column-scale update from previous iteration's partials.
  // cvec[j] RMW is same-thread (same j = tid + k*TPB mapping every iter).
  for (int j = tid; j < N; j += TPB) {
    float A = 0.f;
#pragma unroll
    for (int p = 0; p < SLABS; ++p)
      A += AIn[((size_t)b * SLABS + p) * N + j];
    float cv = cvec[j];
    cvec[j] = cv / (cv * A + EPS);
  }
  __syncthreads();

  float creg[16];
#pragma unroll
  for (int q = 0; q < 2; ++q)
#pragma unroll
    for (int m = 0; m < 8; ++m)
      creg[q * 8 + m] = cvec[q * 512 + l * 8 + m];

  float ca[16];
  if (!LAST) {
#pragma unroll
    for (int k = 0; k < 16; ++k) ca[k] = 0.f;
  }

  // phase b: fully unrolled so r_reg/ca/creg stay register-indexed (no
  // scratch), and the compiler can hoist loads across rows.
#pragma unroll
  for (int t = 0; t < RPW; ++t) {
    size_t rowoff = ((size_t)b * N + (i0 + t)) * N;
    const __half* Erow = E + rowoff;
    float ev[16];
    load16B(Erow + l * 8, ev);
    load16B(Erow + 512 + l * 8, ev + 8);
    // row sum with new c — 4-accumulator tree instead of a 16-deep chain
    float a0 = 0.f, a1 = 0.f, a2 = 0.f, a3 = 0.f;
#pragma unroll
    for (int k = 0; k < 4; ++k) {
      a0 = fmaf(ev[k], creg[k], a0);
      a1 = fmaf(ev[k + 4], creg[k + 4], a1);
      a2 = fmaf(ev[k + 8], creg[k + 8], a2);
      a3 = fmaf(ev[k + 12], creg[k + 12], a3);
    }
    float acc = (a0 + a1) + (a2 + a3);
#pragma unroll
    for (int off = 32; off > 0; off >>= 1) acc += __shfl_xor(acc, off, 64);
    float ro = r_reg[t];
    float rn = ro / (ro * acc + EPS);
    r_reg[t] = rn;
    if (LAST) {
      float* Mrow = M + rowoff;
#pragma unroll
      for (int q = 0; q < 2; ++q)
#pragma unroll
        for (int v = 0; v < 2; ++v) {
          int k = q * 8 + v * 4;
          float4 o = make_float4(ev[k] * rn * creg[k],
                                 ev[k + 1] * rn * creg[k + 1],
                                 ev[k + 2] * rn * creg[k + 2],
                                 ev[k + 3] * rn * creg[k + 3]);
          *reinterpret_cast<float4*>(Mrow + q * 512 + l * 8 + v * 4) = o;
        }
    } else {
      // next iteration's column partials from the SAME registers
#pragma unroll
      for (int k = 0; k < 16; ++k) ca[k] = fmaf(ev[k], rn, ca[k]);
    }
  }

  if (!LAST) {
#pragma unroll
    for (int q = 0; q < 2; ++q)
#pragma unroll
      for (int v = 0; v < 2; ++v) {
        int k = q * 8 + v * 4;
        *reinterpret_cast<float4*>(&red[w][q * 512 + l * 8 + v * 4]) =
            make_float4(ca[k], ca[k + 1], ca[k + 2], ca[k + 3]);
      }
    __syncthreads();
    for (int j = tid; j < N; j += TPB) {
      float a = 0.f;
#pragma unroll
      for (int p = 0; p < WAVES; ++p) a += red[p][j];
      AOut[((size_t)b * SLABS + s) * N + j] = a;
    }
  }
}

// ---------------------------------------------------------------------------
// Persistent kernel: init (E=exp(H), iter-0 partials) + 20 iterations.
// grid = 512 blocks of 512 threads -> 2 blocks/CU guaranteed co-resident
// (LDS 36 KB/block, VGPR capped at 128 by launch_bounds).
// ---------------------------------------------------------------------------
__global__ __launch_bounds__(TPB, 4) void k_mega(
    const float* __restrict__ H, __half* __restrict__ E,
    float* __restrict__ Ap0, float* __restrict__ Ap1, float* __restrict__ M) {
  __shared__ float cvec[N];
  __shared__ float red[WAVES][N];
  const int b = blockIdx.x / SLABS, s = blockIdx.x % SLABS;
  const int tid = threadIdx.x, w = tid >> 6, l = tid & 63;
  const int i0 = s * RPB + w * RPW;

  // ---- init: E = exp(H) (rounded-to-fp16), iteration-0 column partials ----
  {
    float ca[16];
#pragma unroll
    for (int k = 0; k < 16; ++k) ca[k] = 0.f;
    for (int t = 0; t < RPW; ++t) {
      size_t rowoff = ((size_t)b * N + (i0 + t)) * N;
      const float* Hrow = H + rowoff;
      __half* Erow = E + rowoff;
#pragma unroll
      for (int q = 0; q < 4; ++q) {
        int c0 = q * 256 + l * 4;
        float4 h = *reinterpret_cast<const float4*>(Hrow + c0);
        __half2 p0 = __floats2half2_rn(__expf(h.x), __expf(h.y));
        __half2 p1 = __floats2half2_rn(__expf(h.z), __expf(h.w));
        uint2 u;
        u.x = *reinterpret_cast<unsigned*>(&p0);
        u.y = *reinterpret_cast<unsigned*>(&p1);
        *reinterpret_cast<uint2*>(Erow + c0) = u;
        // accumulate the ROUNDED values so partials match stored E
        float2 r0 = __half22float2(p0), r1 = __half22float2(p1);
        ca[q * 4 + 0] += r0.x; ca[q * 4 + 1] += r0.y;
        ca[q * 4 + 2] += r1.x; ca[q * 4 + 3] += r1.y;
      }
    }
#pragma unroll
    for (int q = 0; q < 4; ++q)
      *reinterpret_cast<float4*>(&red[w][q * 256 + l * 4]) =
          make_float4(ca[q * 4], ca[q * 4 + 1], ca[q * 4 + 2], ca[q * 4 + 3]);
    for (int j = tid; j < N; j += TPB) cvec[j] = 1.f;
    __syncthreads();
    for (int j = tid; j < N; j += TPB) {
      float a = 0.f;
#pragma unroll
      for (int p = 0; p < WAVES; ++p) a += red[p][j];
      Ap0[((size_t)b * SLABS + s) * N + j] = a;
    }
  }

  float r_reg[RPW];
#pragma unroll
  for (int t = 0; t < RPW; ++t) r_reg[t] = 1.f;

  cg::grid_group grid = cg::this_grid();
  __threadfence();
  grid.sync();

  // 19 full iterations producing next-iteration partials
  for (int it = 0; it < NITER - 1; ++it) {
    const float* AIn = (it & 1) ? Ap1 : Ap0;
    float* AOut = (it & 1) ? Ap0 : Ap1;
    sk_iter<false>(E, AIn, AOut, M, r_reg, red, cvec, b, s, tid, w, l, i0);
    __threadfence();
    grid.sync();
  }
  // epilogue iteration writes M = r*E*c directly
  {
    const float* AIn = ((NITER - 1) & 1) ? Ap1 : Ap0;
    sk_iter<true>(E, AIn, nullptr, M, r_reg, red, cvec, b, s, tid, w, l, i0);
  }
}

// ---------------------------------------------------------------------------
// Legacy multi-launch path (fallback: coop-launch failure, or fp32/no-ws).
// ---------------------------------------------------------------------------
template <typename ET>
__global__ __launch_bounds__(TPB, 4) void k_init(const float* __restrict__ H,
                                                 ET* __restrict__ E,
                                                 float* __restrict__ Apart0) {
  __shared__ float red[WAVES][N];
  int b = blockIdx.x / SLABS, s = blockIdx.x % SLABS;
  int tid = threadIdx.x, w = tid >> 6, l = tid & 63;
  float ca[16];
#pragma unroll
  for (int k = 0; k < 16; ++k) ca[k] = 0.f;
  int i0 = s * RPB + w * RPW;
  for (int t = 0; t < RPW; ++t) {
    size_t rowoff = ((size_t)b * N + (i0 + t)) * N;
    const float* Hrow = H + rowoff;
#pragma unroll
    for (int q = 0; q < 4; ++q) {
      int c0 = q * 256 + l * 4;
      float4 h = *reinterpret_cast<const float4*>(Hrow + c0);
      float e0 = __expf(h.x), e1 = __expf(h.y), e2 = __expf(h.z), e3 = __expf(h.w);
      if constexpr (sizeof(ET) == 2) {
        __half2 p0 = __floats2half2_rn(e0, e1);
        __half2 p1 = __floats2half2_rn(e2, e3);
        uint2 u;
        u.x = *reinterpret_cast<unsigned*>(&p0);
        u.y = *reinterpret_cast<unsigned*>(&p1);
        *reinterpret_cast<uint2*>((__half*)(E + rowoff) + c0) = u;
        float2 r0 = __half22float2(p0), r1 = __half22float2(p1);
        ca[q * 4 + 0] += r0.x; ca[q * 4 + 1] += r0.y;
        ca[q * 4 + 2] += r1.x; ca[q * 4 + 3] += r1.y;
      } else {
        *reinterpret_cast<float4*>((float*)(E + rowoff) + c0) =
            make_float4(e0, e1, e2, e3);
        ca[q * 4 + 0] += e0; ca[q * 4 + 1] += e1;
        ca[q * 4 + 2] += e2; ca[q * 4 + 3] += e3;
      }
    }
  }
#pragma unroll
  for (int q = 0; q < 4; ++q)
    *reinterpret_cast<float4*>(&red[w][q * 256 + l * 4]) =
        make_float4(ca[q * 4], ca[q * 4 + 1], ca[q * 4 + 2], ca[q * 4 + 3]);
  __syncthreads();
  for (int j = tid; j < N; j += TPB) {
    float a = 0.f;
#pragma unroll
    for (int p = 0; p < WAVES; ++p) a += red[p][j];
    Apart0[((size_t)b * SLABS + s) * N + j] = a;
  }
}

template <typename ET, bool FIRST, bool LAST>
__global__ __launch_bounds__(TPB, 4) void k_pass(
    const ET* E, const float* __restrict__ ApartIn, float* __restrict__ ApartOut,
    const float* __restrict__ cIn, float* __restrict__ cOut,
    float* __restrict__ rbuf, float* M) {
  constexpr int CPL = VT<ET>::CPL, ST = VT<ET>::STEPS;
  __shared__ float cs[N];
  __shared__ float red[WAVES][N];
  int b = blockIdx.x / SLABS, s = blockIdx.x % SLABS;
  int tid = threadIdx.x, w = tid >> 6, l = tid & 63;

  for (int j = tid; j < N; j += TPB) {
    float A = 0.f;
#pragma unroll
    for (int p = 0; p < SLABS; ++p)
      A += ApartIn[((size_t)b * SLABS + p) * N + j];
    float cn;
    if (FIRST) {
      cn = 1.f / (A + EPS);
    } else {
      float cv = cIn[(size_t)b * N + j];
      cn = cv / (cv * A + EPS);
    }
    cs[j] = cn;
    if (!LAST && s == 0) cOut[(size_t)b * N + j] = cn;
  }
  __syncthreads();

  float creg[ST * CPL];
#pragma unroll
  for (int q = 0; q < ST; ++q)
#pragma unroll
    for (int m = 0; m < CPL; ++m)
      creg[q * CPL + m] = cs[q * (64 * CPL) + l * CPL + m];

  float ca[ST * CPL];
#pragma unroll
  for (int k = 0; k < ST * CPL; ++k) ca[k] = 0.f;

  int i0 = s * RPB + w * RPW;
#pragma unroll 2
  for (int t = 0; t < RPW; ++t) {
    int i = i0 + t;
    size_t rowoff = ((size_t)b * N + i) * N;
    const ET* Erow = E + rowoff;
    float ev[ST * CPL];
#pragma unroll
    for (int q = 0; q < ST; ++q)
      load16B(Erow + q * (64 * CPL) + l * CPL, &ev[q * CPL]);
    float acc = 0.f;
#pragma unroll
    for (int k = 0; k < ST * CPL; ++k) acc = fmaf(ev[k], creg[k], acc);
#pragma unroll
    for (int off = 32; off > 0; off >>= 1) acc += __shfl_xor(acc, off, 64);
    float ro = FIRST ? 1.f : rbuf[(size_t)b * N + i];
    float rn = ro / (ro * acc + EPS);
    if (LAST) {
      float* Mrow = M + rowoff;
#pragma unroll
      for (int q = 0; q < ST; ++q)
#pragma unroll
        for (int v = 0; v < CPL / 4; ++v) {
          int k = q * CPL + v * 4;
          float4 o = make_float4(ev[k] * rn * creg[k],
                                 ev[k + 1] * rn * creg[k + 1],
                                 ev[k + 2] * rn * creg[k + 2],
                                 ev[k + 3] * rn * creg[k + 3]);
          *reinterpret_cast<float4*>(Mrow + q * (64 * CPL) + l * CPL + v * 4) = o;
        }
    } else {
      if (l == 0) rbuf[(size_t)b * N + i] = rn;
#pragma unroll
      for (int k = 0; k < ST * CPL; ++k) ca[k] = fmaf(ev[k], rn, ca[k]);
    }
  }

  if (!LAST) {
#pragma unroll
    for (int q = 0; q < ST; ++q)
#pragma unroll
      for (int v = 0; v < CPL / 4; ++v) {
        int k = q * CPL + v * 4;
        *reinterpret_cast<float4*>(&red[w][q * (64 * CPL) + l * CPL + v * 4]) =
            make_float4(ca[k], ca[k + 1], ca[k + 2], ca[k + 3]);
      }
    __syncthreads();
    for (int j = tid; j < N; j += TPB) {
      float a = 0.f;
#pragma unroll
      for (int p = 0; p < WAVES; ++p) a += red[p][j];
      ApartOut[((size_t)b * SLABS + s) * N + j] = a;
    }
  }
}

template <typename ET>
static void run(const float* H, ET* E, float* base, float* M, hipStream_t st) {
  float* Ap[2] = {base, base + (size_t)NB * SLABS * N};
  float* c0 = base + 2 * (size_t)NB * SLABS * N;
  float* cb[2] = {c0, c0 + (size_t)NB * N};
  float* r = c0 + 2 * (size_t)NB * N;
  dim3 g(NB * SLABS), blk(TPB);
  k_init<ET><<<g, blk, 0, st>>>(H, E, Ap[0]);
  for (int j = 0; j < NITER; ++j) {
    const float* ApI = Ap[j & 1];
    float* ApO = Ap[(j + 1) & 1];
    const float* cI = cb[j & 1];
    float* cO = cb[(j + 1) & 1];
    if (j == 0)
      k_pass<ET, true, false><<<g, blk, 0, st>>>(E, ApI, ApO, cI, cO, r, M);
    else if (j == NITER - 1)
      k_pass<ET, false, true><<<g, blk, 0, st>>>(E, ApI, ApO, cI, cO, r, M);
    else
      k_pass<ET, false, false><<<g, blk, 0, st>>>(E, ApI, ApO, cI, cO, r, M);
  }
}

extern "C" void kernel_launch(void* const* d_in, const int* in_sizes, int n_in,
                              void* d_out, int out_size, void* d_ws, size_t ws_size,
                              hipStream_t stream) {
  const float* H = (const float*)d_in[0];
  float* M = (float*)d_out;
  const size_t smallFloats = 2 * (size_t)NB * SLABS * N + 3 * (size_t)NB * N;
  const size_t eBytes = (size_t)NB * N * N * sizeof(__half);  // 128 MB
  if (ws_size >= eBytes + smallFloats * sizeof(float)) {
    __half* E = (__half*)d_ws;
    float* base = (float*)((char*)d_ws + eBytes);
    float* Ap0 = base;
    float* Ap1 = base + (size_t)NB * SLABS * N;
    void* args[5] = {(void*)&H, (void*)&E, (void*)&Ap0, (void*)&Ap1, (void*)&M};
    hipError_t err = hipLaunchCooperativeKernel(
        reinterpret_cast<void*>(&k_mega), dim3(NB * SLABS), dim3(TPB), args, 0,
        stream);
    if (err != hipSuccess) {
      // coop launch unavailable (e.g. capture restriction): legacy path
      run<__half>(H, E, base, M, stream);
    }
  } else {
    // fallback: fp32 E aliased with the output buffer, scaled in place on pass 20
    run<float>(H, M, (float*)d_ws, M, stream);
  }
}

// Round 2
// 2635.984 us; speedup vs baseline: 2.1411x; 2.1411x over previous
//
#include <hip/hip_runtime.h>
#include <hip/hip_fp16.h>

// Sinkhorn-Knopp, factorized M = diag(r) * exp(H) * diag(c).
// V3: back to the proven 21-launch structure (V1 = 1062 us). Change is
// confined to k_pass phase b: manual 2-row interleave with explicit
// double-buffered next-pair prefetch (4 named ev buffers, static indexing)
// to raise per-wave memory-level parallelism and overlap the serial
// shuffle-reduce/divide chains of two rows.
// E stored fp16 (128 MB -> Infinity-Cache resident across the 20 passes).

constexpr int NB    = 64;
constexpr int N     = 1024;
constexpr int SLABS = 8;            // blocks per batch
constexpr int TPB   = 512;          // threads per block (8 waves)
constexpr int WAVES = TPB / 64;     // 8
constexpr int RPB   = N / SLABS;    // 128 rows per block
constexpr int RPW   = RPB / WAVES;  // 16 rows per wave
constexpr int NITER = 20;
constexpr float EPS = 1e-8f;

static_assert(RPW == 16, "pair schedule below assumes 16 rows/wave");

template <typename ET> struct VT;
template <> struct VT<__half> { static constexpr int CPL = 8, STEPS = 2; };
template <> struct VT<float>  { static constexpr int CPL = 4, STEPS = 4; };

// 16 B load -> CPL floats
__device__ inline void load16B(const __half* p, float* f) {
  uint4 u = *reinterpret_cast<const uint4*>(p);
  float2 t;
  t = __half22float2(*reinterpret_cast<__half2*>(&u.x)); f[0] = t.x; f[1] = t.y;
  t = __half22float2(*reinterpret_cast<__half2*>(&u.y)); f[2] = t.x; f[3] = t.y;
  t = __half22float2(*reinterpret_cast<__half2*>(&u.z)); f[4] = t.x; f[5] = t.y;
  t = __half22float2(*reinterpret_cast<__half2*>(&u.w)); f[6] = t.x; f[7] = t.y;
}
__device__ inline void load16B(const float* p, float* f) {
  float4 v = *reinterpret_cast<const float4*>(p);
  f[0] = v.x; f[1] = v.y; f[2] = v.z; f[3] = v.w;
}

// one row of E (16 floats worth) -> registers
template <typename ET>
__device__ __forceinline__ void load_row(const ET* Erow, int l, float (&f)[16]) {
  constexpr int CPL = VT<ET>::CPL, ST = VT<ET>::STEPS;
#pragma unroll
  for (int q = 0; q < ST; ++q)
    load16B(Erow + q * (64 * CPL) + l * CPL, &f[q * CPL]);
}

// ---- init: E = exp(H), plus iteration-1 column partials (r = 1) ----
template <typename ET>
__global__ __launch_bounds__(TPB, 4) void k_init(const float* __restrict__ H,
                                                 ET* __restrict__ E,
                                                 float* __restrict__ Apart0) {
  __shared__ float red[WAVES][N];
  int b = blockIdx.x / SLABS, s = blockIdx.x % SLABS;
  int tid = threadIdx.x, w = tid >> 6, l = tid & 63;
  float ca[16];
#pragma unroll
  for (int k = 0; k < 16; ++k) ca[k] = 0.f;
  int i0 = s * RPB + w * RPW;
  for (int t = 0; t < RPW; ++t) {
    size_t rowoff = ((size_t)b * N + (i0 + t)) * N;
    const float* Hrow = H + rowoff;
#pragma unroll
    for (int q = 0; q < 4; ++q) {
      int c0 = q * 256 + l * 4;
      float4 h = *reinterpret_cast<const float4*>(Hrow + c0);
      float e0 = __expf(h.x), e1 = __expf(h.y), e2 = __expf(h.z), e3 = __expf(h.w);
      if constexpr (sizeof(ET) == 2) {
        __half2 p0 = __floats2half2_rn(e0, e1);
        __half2 p1 = __floats2half2_rn(e2, e3);
        uint2 u;
        u.x = *reinterpret_cast<unsigned*>(&p0);
        u.y = *reinterpret_cast<unsigned*>(&p1);
        *reinterpret_cast<uint2*>((__half*)(E + rowoff) + c0) = u;
        // accumulate the ROUNDED values so partials match stored E
        float2 r0 = __half22float2(p0), r1 = __half22float2(p1);
        ca[q * 4 + 0] += r0.x; ca[q * 4 + 1] += r0.y;
        ca[q * 4 + 2] += r1.x; ca[q * 4 + 3] += r1.y;
      } else {
        *reinterpret_cast<float4*>((float*)(E + rowoff) + c0) =
            make_float4(e0, e1, e2, e3);
        ca[q * 4 + 0] += e0; ca[q * 4 + 1] += e1;
        ca[q * 4 + 2] += e2; ca[q * 4 + 3] += e3;
      }
    }
  }
#pragma unroll
  for (int q = 0; q < 4; ++q)
    *reinterpret_cast<float4*>(&red[w][q * 256 + l * 4]) =
        make_float4(ca[q * 4], ca[q * 4 + 1], ca[q * 4 + 2], ca[q * 4 + 3]);
  __syncthreads();
  for (int j = tid; j < N; j += TPB) {
    float a = 0.f;
#pragma unroll
    for (int p = 0; p < WAVES; ++p) a += red[p][j];
    Apart0[((size_t)b * SLABS + s) * N + j] = a;
  }
}

// ---- compute one interleaved pair of rows (i, i+1) ----
template <typename ET, bool FIRST, bool LAST>
__device__ __forceinline__ void pair_body(float* M, float* __restrict__ rbuf,
                                          size_t brow, int i, int l,
                                          const float (&creg)[16],
                                          float (&ca)[16],
                                          const float (&ev0)[16],
                                          const float (&ev1)[16]) {
  constexpr int CPL = VT<ET>::CPL, ST = VT<ET>::STEPS;
  float ro0 = 1.f, ro1 = 1.f;
  if (!FIRST) {  // uniform loads; latency overlaps the FMA/shuffle chains
    ro0 = rbuf[brow + i];
    ro1 = rbuf[brow + i + 1];
  }
  // 4-accumulator trees for both rows, interleaved
  float a00 = 0.f, a01 = 0.f, a02 = 0.f, a03 = 0.f;
  float a10 = 0.f, a11 = 0.f, a12 = 0.f, a13 = 0.f;
#pragma unroll
  for (int k = 0; k < 4; ++k) {
    a00 = fmaf(ev0[k],      creg[k],      a00);
    a01 = fmaf(ev0[k + 4],  creg[k + 4],  a01);
    a02 = fmaf(ev0[k + 8],  creg[k + 8],  a02);
    a03 = fmaf(ev0[k + 12], creg[k + 12], a03);
    a10 = fmaf(ev1[k],      creg[k],      a10);
    a11 = fmaf(ev1[k + 4],  creg[k + 4],  a11);
    a12 = fmaf(ev1[k + 8],  creg[k + 8],  a12);
    a13 = fmaf(ev1[k + 12], creg[k + 12], a13);
  }
  float acc0 = (a00 + a01) + (a02 + a03);
  float acc1 = (a10 + a11) + (a12 + a13);
  // two independent butterfly reduces, ping-ponged so DS latencies overlap
#pragma unroll
  for (int off = 32; off > 0; off >>= 1) {
    float s0 = __shfl_xor(acc0, off, 64);
    float s1 = __shfl_xor(acc1, off, 64);
    acc0 += s0;
    acc1 += s1;
  }
  float rn0 = ro0 / (ro0 * acc0 + EPS);
  float rn1 = ro1 / (ro1 * acc1 + EPS);
  if (LAST) {
    float* Mrow0 = M + (brow + i) * (size_t)N;
    float* Mrow1 = M + (brow + i + 1) * (size_t)N;
#pragma unroll
    for (int q = 0; q < ST; ++q)
#pragma unroll
      for (int v = 0; v < CPL / 4; ++v) {
        int k = q * CPL + v * 4;
        float4 o0 = make_float4(ev0[k] * rn0 * creg[k],
                                ev0[k + 1] * rn0 * creg[k + 1],
                                ev0[k + 2] * rn0 * creg[k + 2],
                                ev0[k + 3] * rn0 * creg[k + 3]);
        float4 o1 = make_float4(ev1[k] * rn1 * creg[k],
                                ev1[k + 1] * rn1 * creg[k + 1],
                                ev1[k + 2] * rn1 * creg[k + 2],
                                ev1[k + 3] * rn1 * creg[k + 3]);
        *reinterpret_cast<float4*>(Mrow0 + q * (64 * CPL) + l * CPL + v * 4) = o0;
        *reinterpret_cast<float4*>(Mrow1 + q * (64 * CPL) + l * CPL + v * 4) = o1;
      }
  } else {
    if (l == 0) {
      rbuf[brow + i] = rn0;
      rbuf[brow + i + 1] = rn1;
    }
    // next iteration's column partials from the SAME registers
#pragma unroll
    for (int k = 0; k < 16; ++k) {
      ca[k] = fmaf(ev0[k], rn0, ca[k]);
      ca[k] = fmaf(ev1[k], rn1, ca[k]);
    }
  }
}

// ---- one Sinkhorn iteration per launch ----
// NOTE: E and M deliberately NOT both __restrict__ — fp32 fallback aliases them.
template <typename ET, bool FIRST, bool LAST>
__global__ __launch_bounds__(TPB, 4) void k_pass(
    const ET* E, const float* __restrict__ ApartIn, float* __restrict__ ApartOut,
    const float* __restrict__ cIn, float* __restrict__ cOut,
    float* __restrict__ rbuf, float* M) {
  constexpr int CPL = VT<ET>::CPL, ST = VT<ET>::STEPS;
  __shared__ float cs[N];
  __shared__ float red[WAVES][N];
  int b = blockIdx.x / SLABS, s = blockIdx.x % SLABS;
  int tid = threadIdx.x, w = tid >> 6, l = tid & 63;

  // phase a: column-scale update from previous pass's partials
  for (int j = tid; j < N; j += TPB) {
    float A = 0.f;
#pragma unroll
    for (int p = 0; p < SLABS; ++p)
      A += ApartIn[((size_t)b * SLABS + p) * N + j];
    float cn;
    if (FIRST) {
      cn = 1.f / (A + EPS);
    } else {
      float cv = cIn[(size_t)b * N + j];
      cn = cv / (cv * A + EPS);
    }
    cs[j] = cn;
    if (!LAST && s == 0) cOut[(size_t)b * N + j] = cn;
  }
  __syncthreads();

  float creg[16];
#pragma unroll
  for (int q = 0; q < ST; ++q)
#pragma unroll
    for (int m = 0; m < CPL; ++m)
      creg[q * CPL + m] = cs[q * (64 * CPL) + l * CPL + m];

  float ca[16];
#pragma unroll
  for (int k = 0; k < 16; ++k) ca[k] = 0.f;

  const int i0 = s * RPB + w * RPW;
  const size_t brow = (size_t)b * N;

  // phase b: 8 pairs, 2 rows interleaved, next pair prefetched into the
  // alternate buffer set BEFORE the current pair's reduce chain.
  float evA0[16], evA1[16], evB0[16], evB1[16];
  load_row(E + (brow + i0 + 0) * (size_t)N, l, evA0);
  load_row(E + (brow + i0 + 1) * (size_t)N, l, evA1);

#define SK_PAIR(T, C0, C1, X0, X1, PF)                                        \
  do {                                                                        \
    if (PF) {                                                                 \
      load_row(E + (brow + i0 + (T) + 2) * (size_t)N, l, X0);                 \
      load_row(E + (brow + i0 + (T) + 3) * (size_t)N, l, X1);                 \
    }                                                                         \
    pair_body<ET, FIRST, LAST>(M, rbuf, brow, i0 + (T), l, creg, ca, C0, C1); \
  } while (0)

  SK_PAIR(0,  evA0, evA1, evB0, evB1, true);
  SK_PAIR(2,  evB0, evB1, evA0, evA1, true);
  SK_PAIR(4,  evA0, evA1, evB0, evB1, true);
  SK_PAIR(6,  evB0, evB1, evA0, evA1, true);
  SK_PAIR(8,  evA0, evA1, evB0, evB1, true);
  SK_PAIR(10, evB0, evB1, evA0, evA1, true);
  SK_PAIR(12, evA0, evA1, evB0, evB1, true);
  SK_PAIR(14, evB0, evB1, evA0, evA1, false);
#undef SK_PAIR

  if (!LAST) {
#pragma unroll
    for (int q = 0; q < ST; ++q)
#pragma unroll
      for (int v = 0; v < CPL / 4; ++v) {
        int k = q * CPL + v * 4;
        *reinterpret_cast<float4*>(&red[w][q * (64 * CPL) + l * CPL + v * 4]) =
            make_float4(ca[k], ca[k + 1], ca[k + 2], ca[k + 3]);
      }
    __syncthreads();
    for (int j = tid; j < N; j += TPB) {
      float a = 0.f;
#pragma unroll
      for (int p = 0; p < WAVES; ++p) a += red[p][j];
      ApartOut[((size_t)b * SLABS + s) * N + j] = a;
    }
  }
}

template <typename ET>
static void run(const float* H, ET* E, float* base, float* M, hipStream_t st) {
  float* Ap[2] = {base, base + (size_t)NB * SLABS * N};
  float* c0 = base + 2 * (size_t)NB * SLABS * N;
  float* cb[2] = {c0, c0 + (size_t)NB * N};
  float* r = c0 + 2 * (size_t)NB * N;
  dim3 g(NB * SLABS), blk(TPB);
  k_init<ET><<<g, blk, 0, st>>>(H, E, Ap[0]);
  for (int j = 0; j < NITER; ++j) {
    const float* ApI = Ap[j & 1];
    float* ApO = Ap[(j + 1) & 1];
    const float* cI = cb[j & 1];
    float* cO = cb[(j + 1) & 1];
    if (j == 0)
      k_pass<ET, true, false><<<g, blk, 0, st>>>(E, ApI, ApO, cI, cO, r, M);
    else if (j == NITER - 1)
      k_pass<ET, false, true><<<g, blk, 0, st>>>(E, ApI, ApO, cI, cO, r, M);
    else
      k_pass<ET, false, false><<<g, blk, 0, st>>>(E, ApI, ApO, cI, cO, r, M);
  }
}

extern "C" void kernel_launch(void* const* d_in, const int* in_sizes, int n_in,
                              void* d_out, int out_size, void* d_ws, size_t ws_size,
                              hipStream_t stream) {
  const float* H = (const float*)d_in[0];
  float* M = (float*)d_out;
  const size_t smallFloats = 2 * (size_t)NB * SLABS * N + 3 * (size_t)NB * N;
  const size_t eBytes = (size_t)NB * N * N * sizeof(__half);  // 128 MB
  if (ws_size >= eBytes + smallFloats * sizeof(float)) {
    // fast path: fp16 E in workspace (L3-resident across passes)
    run<__half>(H, (__half*)d_ws, (float*)((char*)d_ws + eBytes), M, stream);
  } else {
    // fallback: fp32 E aliased with the output buffer, scaled in place on pass 20
    run<float>(H, M, (float*)d_ws, M, stream);
  }
}

// Round 5
// 1034.617 us; speedup vs baseline: 5.4550x; 2.5478x over previous
//
#include <hip/hip_runtime.h>
#include <hip/hip_fp16.h>

// Sinkhorn-Knopp, factorized M = diag(r) * exp(H) * diag(c).
// V5 = V4 minus the forced 64-VGPR cap (suspected deterministic build
// failure: __launch_bounds__(512,8) can make register allocation fail
// hard on gfx950; V1-V3 all compiled fine under (512,4)).
// Kept from V4:
//  (a) r-values staged into LDS in phase a -- removes the per-row GLOBAL
//      rbuf load whose first use forced a vmcnt drain inside the row
//      dependence chain (V3 post-mortem lesson).
//  (b) SLABS=16 -> grid 1024 blocks; if natural VGPR count <= 64 (k_mega
//      round-1 evidence says the live set fits in 64) this yields
//      4 blocks/CU = 32 waves/CU without forcing the allocator.
// E stored fp16 (128 MB -> Infinity-Cache resident across the 20 passes).

constexpr int NB    = 64;
constexpr int N     = 1024;
constexpr int SLABS = 16;           // blocks per batch
constexpr int TPB   = 512;          // threads per block (8 waves)
constexpr int WAVES = TPB / 64;     // 8
constexpr int RPB   = N / SLABS;    // 64 rows per block
constexpr int RPW   = RPB / WAVES;  // 8 rows per wave
constexpr int NITER = 20;
constexpr float EPS = 1e-8f;

template <typename ET> struct VT;
template <> struct VT<__half> { static constexpr int CPL = 8, STEPS = 2; };
template <> struct VT<float>  { static constexpr int CPL = 4, STEPS = 4; };

// 16 B load -> CPL floats
__device__ inline void load16B(const __half* p, float* f) {
  uint4 u = *reinterpret_cast<const uint4*>(p);
  float2 t;
  t = __half22float2(*reinterpret_cast<__half2*>(&u.x)); f[0] = t.x; f[1] = t.y;
  t = __half22float2(*reinterpret_cast<__half2*>(&u.y)); f[2] = t.x; f[3] = t.y;
  t = __half22float2(*reinterpret_cast<__half2*>(&u.z)); f[4] = t.x; f[5] = t.y;
  t = __half22float2(*reinterpret_cast<__half2*>(&u.w)); f[6] = t.x; f[7] = t.y;
}
__device__ inline void load16B(const float* p, float* f) {
  float4 v = *reinterpret_cast<const float4*>(p);
  f[0] = v.x; f[1] = v.y; f[2] = v.z; f[3] = v.w;
}

// ---- init: E = exp(H), plus iteration-1 column partials (r = 1) ----
template <typename ET>
__global__ __launch_bounds__(TPB, 4) void k_init(const float* __restrict__ H,
                                                 ET* __restrict__ E,
                                                 float* __restrict__ Apart0) {
  __shared__ float red[WAVES][N];
  int b = blockIdx.x / SLABS, s = blockIdx.x % SLABS;
  int tid = threadIdx.x, w = tid >> 6, l = tid & 63;
  float ca[16];
#pragma unroll
  for (int k = 0; k < 16; ++k) ca[k] = 0.f;
  int i0 = s * RPB + w * RPW;
  for (int t = 0; t < RPW; ++t) {
    size_t rowoff = ((size_t)b * N + (i0 + t)) * N;
    const float* Hrow = H + rowoff;
#pragma unroll
    for (int q = 0; q < 4; ++q) {
      int c0 = q * 256 + l * 4;
      float4 h = *reinterpret_cast<const float4*>(Hrow + c0);
      float e0 = __expf(h.x), e1 = __expf(h.y), e2 = __expf(h.z), e3 = __expf(h.w);
      if constexpr (sizeof(ET) == 2) {
        __half2 p0 = __floats2half2_rn(e0, e1);
        __half2 p1 = __floats2half2_rn(e2, e3);
        uint2 u;
        u.x = *reinterpret_cast<unsigned*>(&p0);
        u.y = *reinterpret_cast<unsigned*>(&p1);
        *reinterpret_cast<uint2*>((__half*)(E + rowoff) + c0) = u;
        // accumulate the ROUNDED values so partials match stored E
        float2 r0 = __half22float2(p0), r1 = __half22float2(p1);
        ca[q * 4 + 0] += r0.x; ca[q * 4 + 1] += r0.y;
        ca[q * 4 + 2] += r1.x; ca[q * 4 + 3] += r1.y;
      } else {
        *reinterpret_cast<float4*>((float*)(E + rowoff) + c0) =
            make_float4(e0, e1, e2, e3);
        ca[q * 4 + 0] += e0; ca[q * 4 + 1] += e1;
        ca[q * 4 + 2] += e2; ca[q * 4 + 3] += e3;
      }
    }
  }
#pragma unroll
  for (int q = 0; q < 4; ++q)
    *reinterpret_cast<float4*>(&red[w][q * 256 + l * 4]) =
        make_float4(ca[q * 4], ca[q * 4 + 1], ca[q * 4 + 2], ca[q * 4 + 3]);
  __syncthreads();
  for (int j = tid; j < N; j += TPB) {
    float a = 0.f;
#pragma unroll
    for (int p = 0; p < WAVES; ++p) a += red[p][j];
    Apart0[((size_t)b * SLABS + s) * N + j] = a;
  }
}

// ---- one Sinkhorn iteration per launch ----
// NOTE: E and M deliberately NOT both __restrict__ — fp32 fallback aliases them.
template <typename ET, bool FIRST, bool LAST>
__global__ __launch_bounds__(TPB, 4) void k_pass(
    const ET* E, const float* __restrict__ ApartIn, float* __restrict__ ApartOut,
    const float* __restrict__ cIn, float* __restrict__ cOut,
    float* __restrict__ rbuf, float* M) {
  constexpr int CPL = VT<ET>::CPL, ST = VT<ET>::STEPS;
  __shared__ float cs[N];
  __shared__ float red[WAVES][N];
  __shared__ float rs[RPB];
  int b = blockIdx.x / SLABS, s = blockIdx.x % SLABS;
  int tid = threadIdx.x, w = tid >> 6, l = tid & 63;

  // phase a: column-scale update from previous pass's partials,
  // plus staging this block's r-slice into LDS (keeps the row loop's
  // vmem stream pure-E so the compiler can pipeline it).
  if (tid < RPB)
    rs[tid] = FIRST ? 1.f : rbuf[(size_t)b * N + s * RPB + tid];
  for (int j = tid; j < N; j += TPB) {
    float A = 0.f;
#pragma unroll
    for (int p = 0; p < SLABS; ++p)
      A += ApartIn[((size_t)b * SLABS + p) * N + j];
    float cn;
    if (FIRST) {
      cn = 1.f / (A + EPS);
    } else {
      float cv = cIn[(size_t)b * N + j];
      cn = cv / (cv * A + EPS);
    }
    cs[j] = cn;
    if (!LAST && s == 0) cOut[(size_t)b * N + j] = cn;
  }
  __syncthreads();

  float creg[ST * CPL];
#pragma unroll
  for (int q = 0; q < ST; ++q)
#pragma unroll
    for (int m = 0; m < CPL; ++m)
      creg[q * CPL + m] = cs[q * (64 * CPL) + l * CPL + m];

  float ca[ST * CPL];
#pragma unroll
  for (int k = 0; k < ST * CPL; ++k) ca[k] = 0.f;

  int i0 = s * RPB + w * RPW;
#pragma unroll 2
  for (int t = 0; t < RPW; ++t) {
    int i = i0 + t;
    size_t rowoff = ((size_t)b * N + i) * N;
    const ET* Erow = E + rowoff;
    float ev[ST * CPL];
#pragma unroll
    for (int q = 0; q < ST; ++q)
      load16B(Erow + q * (64 * CPL) + l * CPL, &ev[q * CPL]);
    // row sum with new c — 4-accumulator tree
    float a0 = 0.f, a1 = 0.f, a2 = 0.f, a3 = 0.f;
#pragma unroll
    for (int k = 0; k < ST * CPL / 4; ++k) {
      a0 = fmaf(ev[k], creg[k], a0);
      a1 = fmaf(ev[k + 4], creg[k + 4], a1);
      a2 = fmaf(ev[k + 8], creg[k + 8], a2);
      a3 = fmaf(ev[k + 12], creg[k + 12], a3);
    }
    float acc = (a0 + a1) + (a2 + a3);
#pragma unroll
    for (int off = 32; off > 0; off >>= 1) acc += __shfl_xor(acc, off, 64);
    // row-scale update: previous r from LDS (broadcast read, no vmcnt)
    float ro = rs[w * RPW + t];
    float rn = ro / (ro * acc + EPS);
    if (LAST) {
      float* Mrow = M + rowoff;
#pragma unroll
      for (int q = 0; q < ST; ++q)
#pragma unroll
        for (int v = 0; v < CPL / 4; ++v) {
          int k = q * CPL + v * 4;
          float4 o = make_float4(ev[k] * rn * creg[k],
                                 ev[k + 1] * rn * creg[k + 1],
                                 ev[k + 2] * rn * creg[k + 2],
                                 ev[k + 3] * rn * creg[k + 3]);
          *reinterpret_cast<float4*>(Mrow + q * (64 * CPL) + l * CPL + v * 4) = o;
        }
    } else {
      if (l == 0) rbuf[(size_t)b * N + i] = rn;
      // next iteration's column partials from the SAME registers
#pragma unroll
      for (int k = 0; k < ST * CPL; ++k) ca[k] = fmaf(ev[k], rn, ca[k]);
    }
  }

  if (!LAST) {
#pragma unroll
    for (int q = 0; q < ST; ++q)
#pragma unroll
      for (int v = 0; v < CPL / 4; ++v) {
        int k = q * CPL + v * 4;
        *reinterpret_cast<float4*>(&red[w][q * (64 * CPL) + l * CPL + v * 4]) =
            make_float4(ca[k], ca[k + 1], ca[k + 2], ca[k + 3]);
      }
    __syncthreads();
    for (int j = tid; j < N; j += TPB) {
      float a = 0.f;
#pragma unroll
      for (int p = 0; p < WAVES; ++p) a += red[p][j];
      ApartOut[((size_t)b * SLABS + s) * N + j] = a;
    }
  }
}

template <typename ET>
static void run(const float* H, ET* E, float* base, float* M, hipStream_t st) {
  float* Ap[2] = {base, base + (size_t)NB * SLABS * N};
  float* c0 = base + 2 * (size_t)NB * SLABS * N;
  float* cb[2] = {c0, c0 + (size_t)NB * N};
  float* r = c0 + 2 * (size_t)NB * N;
  dim3 g(NB * SLABS), blk(TPB);
  k_init<ET><<<g, blk, 0, st>>>(H, E, Ap[0]);
  for (int j = 0; j < NITER; ++j) {
    const float* ApI = Ap[j & 1];
    float* ApO = Ap[(j + 1) & 1];
    const float* cI = cb[j & 1];
    float* cO = cb[(j + 1) & 1];
    if (j == 0)
      k_pass<ET, true, false><<<g, blk, 0, st>>>(E, ApI, ApO, cI, cO, r, M);
    else if (j == NITER - 1)
      k_pass<ET, false, true><<<g, blk, 0, st>>>(E, ApI, ApO, cI, cO, r, M);
    else
      k_pass<ET, false, false><<<g, blk, 0, st>>>(E, ApI, ApO, cI, cO, r, M);
  }
}

extern "C" void kernel_launch(void* const* d_in, const int* in_sizes, int n_in,
                              void* d_out, int out_size, void* d_ws, size_t ws_size,
                              hipStream_t stream) {
  const float* H = (const float*)d_in[0];
  float* M = (float*)d_out;
  const size_t smallFloats = 2 * (size_t)NB * SLABS * N + 3 * (size_t)NB * N;
  const size_t eBytes = (size_t)NB * N * N * sizeof(__half);  // 128 MB
  if (ws_size >= eBytes + smallFloats * sizeof(float)) {
    // fast path: fp16 E in workspace (L3-resident across passes)
    run<__half>(H, (__half*)d_ws, (float*)((char*)d_ws + eBytes), M, stream);
  } else {
    // fallback: fp32 E aliased with the output buffer, scaled in place on pass 20
    run<float>(H, M, (float*)d_ws, M, stream);
  }
}